// Round 13
// baseline (10630.109 us; speedup 1.0000x reference)
//
#include <hip/hip_runtime.h>

// ---------------------------------------------------------------------------
// FastCASSBlock: LN -> selector -> biGRU (input-proj fused per chunk) ->
// out_proj + residual.
// v13: work WITH the allocator. 256-thr scan WG (observed VGPR grant = 256).
// Thread t owns unit t's r,z,n rows: gate math in-thread (no LDS exchange).
// r-rows (128 regs) pinned resident -- demand ~210 < 256 grant, first design
// under budget. z,n rows INTENTIONALLY streamed from L2 per step (256KB/step
// ~1900cyc) via a pre-swizzled coalesced layout whhS[gate][kblk][unit]
// (uvec4 per (t,kblk); lane-consecutive 16B). h-broadcast: 32 uniform
// b128/wave x 4 waves = 128 DS/step (vs v12's 384 = 4600cyc DS-bound).
// Workspace (bytes), ~98 MiB total:
//   xn    f16 [65536,256]  @ 0           (33554432)
//   gray  f32 [65536]      @ 33554432    (262144)
//   flag  i32 [16]         @ 33816576    (256)
//   whhS  uvec4[2][3][32][256] @ 33816832 (786432)  swizzled stream layout
//   out_w f16 [256,512]    @ 34603264    (262144)
//   wcomb f16 [1536,256]   @ 34865408    (786432)
//   badj  f32 [1536]       @ 35651840    (6144)
//   ycat  f16 [65536,512]  @ 35658240    (67108864)
// ---------------------------------------------------------------------------

#define L_   4096
#define CH   32     // scan chunk length (steps)
#define NCH  128    // L_/CH

typedef __attribute__((ext_vector_type(8))) _Float16 half8;
typedef __attribute__((ext_vector_type(2))) _Float16 half2v;
typedef __attribute__((ext_vector_type(4))) float f32x4;
typedef __attribute__((ext_vector_type(4))) unsigned uvec4;

__device__ __forceinline__ unsigned short f2h(float f) {
  _Float16 h = (_Float16)f;
  return __builtin_bit_cast(unsigned short, h);
}
__device__ __forceinline__ float h2f(unsigned short u) {
  return (float)__builtin_bit_cast(_Float16, u);
}
__device__ __forceinline__ float sigm(float x) {
  return __builtin_amdgcn_rcpf(1.f + __expf(-x));
}
__device__ __forceinline__ float tanhf_(float x) {
  return 1.f - 2.f * __builtin_amdgcn_rcpf(1.f + __expf(2.f * x));
}
__device__ __forceinline__ float dot2(unsigned w, unsigned h, float c) {
  return __builtin_amdgcn_fdot2(__builtin_bit_cast(half2v, w),
                                __builtin_bit_cast(half2v, h), c, false);
}

// --------------------------- f32 -> f16 convert ----------------------------
__global__ __launch_bounds__(256) void k_f2h(const float* __restrict__ in,
                                             unsigned short* __restrict__ out,
                                             int n) {
  int i = blockIdx.x * 256 + threadIdx.x;
  if (i < n) out[i] = f2h(in[i]);
}

// ---- whhS[dir][gate][kblk][unit] = uvec4 of whh[gate*256+unit][kblk*8..+8] -
// Coalesced stream layout: lane-consecutive 16B per (kblk, unit-row).
__global__ __launch_bounds__(256) void k_whhS(const float* __restrict__ whh_f,
                                              const float* __restrict__ whh_b,
                                              uvec4* __restrict__ whhS) {
  const int blk = blockIdx.x;            // 0..191 = dir*96 + gate*32 + kblk
  const int dir = blk / 96;
  const int rem = blk - dir * 96;
  const int gate = rem >> 5;
  const int kblk = rem & 31;
  const int t = threadIdx.x;
  const float* src = (dir ? whh_b : whh_f) + (long)(gate * 256 + t) * 256 + kblk * 8;
  unsigned short h[8];
#pragma unroll
  for (int j = 0; j < 8; ++j) h[j] = f2h(src[j]);
  uvec4 v;
  v.x = (unsigned)h[0] | ((unsigned)h[1] << 16);
  v.y = (unsigned)h[2] | ((unsigned)h[3] << 16);
  v.z = (unsigned)h[4] | ((unsigned)h[5] << 16);
  v.w = (unsigned)h[6] | ((unsigned)h[7] << 16);
  whhS[(long)blk * 256 + t] = v;
}

// ------------------- wcomb[n,c] = sum_j wih[n,j]*in_w[j,c] -----------------
__global__ __launch_bounds__(256) void k_wcomb(const float* __restrict__ wih_f,
                                               const float* __restrict__ wih_b,
                                               const float* __restrict__ in_w,
                                               unsigned short* __restrict__ wcomb) {
  const int n = blockIdx.x;  // 0..1535
  const float* wrow = (n < 768) ? (wih_f + (long)n * 512)
                                : (wih_b + (long)(n - 768) * 512);
  const int k = threadIdx.x;  // 0..255
  float acc = 0.f;
  for (int j = 0; j < 512; ++j) acc += wrow[j] * in_w[j * 256 + k];
  wcomb[(long)n * 256 + k] = f2h(acc);
}

// -- badj[n] = bih[n] + sum_j wih[n,j]*in_b[j] (+ bhh[n] for r/z slots) ------
__global__ __launch_bounds__(256) void k_bcomb(const float* __restrict__ wih_f,
                                               const float* __restrict__ wih_b,
                                               const float* __restrict__ in_b,
                                               const float* __restrict__ bih_f,
                                               const float* __restrict__ bih_b,
                                               const float* __restrict__ bhh_f,
                                               const float* __restrict__ bhh_b,
                                               float* __restrict__ badj) {
  int n = blockIdx.x * 256 + threadIdx.x;
  if (n >= 1536) return;
  const int dir = n >= 768;
  const int g = dir ? (n - 768) : n;
  const float* wrow = (dir ? wih_b : wih_f) + (long)g * 512;
  float acc = (dir ? bih_b : bih_f)[g];
  for (int j = 0; j < 512; ++j) acc += wrow[j] * in_b[j];
  if (g < 512) acc += (dir ? bhh_b : bhh_f)[g];  // fold bhh for r,z gates
  badj[n] = acc;
}

// --------------------------- LayerNorm + gray ------------------------------
__global__ __launch_bounds__(256) void k_ln(const float* __restrict__ x,
                                            const float* __restrict__ gamma,
                                            const float* __restrict__ beta,
                                            unsigned short* __restrict__ xn,
                                            float* __restrict__ gray) {
  const int lane = threadIdx.x & 63;
  const long pix = (long)blockIdx.x * 4 + (threadIdx.x >> 6);
  const float4 v = *(const float4*)(x + pix * 256 + lane * 4);
  float s = v.x + v.y + v.z + v.w;
  float s2 = v.x * v.x + v.y * v.y + v.z * v.z + v.w * v.w;
#pragma unroll
  for (int off = 32; off > 0; off >>= 1) {
    s += __shfl_xor(s, off, 64);
    s2 += __shfl_xor(s2, off, 64);
  }
  const float mu = s * (1.f / 256.f);
  const float var = fmaxf(s2 * (1.f / 256.f) - mu * mu, 0.f);
  const float rstd = rsqrtf(var + 1e-5f);
  const float4 gm = *(const float4*)(gamma + lane * 4);
  const float4 bt = *(const float4*)(beta + lane * 4);
  float o0 = (v.x - mu) * rstd * gm.x + bt.x;
  float o1 = (v.y - mu) * rstd * gm.y + bt.y;
  float o2 = (v.z - mu) * rstd * gm.z + bt.z;
  float o3 = (v.w - mu) * rstd * gm.w + bt.w;
  ushort4 o;
  o.x = f2h(o0); o.y = f2h(o1); o.z = f2h(o2); o.w = f2h(o3);
  *(ushort4*)(xn + pix * 256 + lane * 4) = o;
  float gs = o0 + o1 + o2 + o3;
#pragma unroll
  for (int off = 32; off > 0; off >>= 1) gs += __shfl_xor(gs, off, 64);
  if (lane == 0) gray[pix] = gs * (1.f / 256.f);
}

// --------------------- gradient-direction selector -------------------------
__device__ __forceinline__ int refl64(int m) {
  return m < 0 ? -m : (m > 63 ? 126 - m : m);
}

__global__ __launch_bounds__(256) void k_sel(const float* __restrict__ gray,
                                             const float* __restrict__ w1,
                                             const float* __restrict__ b1,
                                             const float* __restrict__ w2,
                                             const float* __restrict__ b2,
                                             int* __restrict__ flag) {
  __shared__ float g[64][65];
  __shared__ float part[4][4];
  const int b = blockIdx.x;
  const int tid = threadIdx.x;
  for (int r = 0; r < 16; ++r) {
    int p = tid + 256 * r;
    g[p >> 6][p & 63] = gray[(long)b * 4096 + p];
  }
  __syncthreads();
  const float S = 66.f / 64.f;
  float sh = 0.f, sv = 0.f, sd = 0.f, sa = 0.f;
  for (int rr = 0; rr < 16; ++rr) {
    int p = tid + 256 * rr;
    int h = p >> 6, w = p & 63;
    float srci = (h + 0.5f) * S - 0.5f;
    int i0 = (int)srci;
    float ai = srci - (float)i0;
    int i1 = i0 + 1; if (i1 > 65) i1 = 65;
    int r0 = refl64(i0 - 1), r1 = refl64(i1 - 1);
    int wl = w ? (w - 1) : 1;
    int wr2 = (w == 63) ? 62 : (w + 1);
    float GH0 = fabsf(g[r0][wr2] - g[r0][wl]);
    float GH1 = fabsf(g[r1][wr2] - g[r1][wl]);
    float ghr = GH0 + ai * (GH1 - GH0);
    float srcj = (w + 0.5f) * S - 0.5f;
    int j0 = (int)srcj;
    float aj = srcj - (float)j0;
    int j1 = j0 + 1; if (j1 > 65) j1 = 65;
    int c0 = refl64(j0 - 1), c1 = refl64(j1 - 1);
    int hu = h ? (h - 1) : 1;
    int hd = (h == 63) ? 62 : (h + 1);
    float GV0 = fabsf(g[hd][c0] - g[hu][c0]);
    float GV1 = fabsf(g[hd][c1] - g[hu][c1]);
    float gvr = GV0 + aj * (GV1 - GV0);
    float wt = ((h == 0 || h == 63) ? 2.f : 3.f) *
               ((w == 0 || w == 63) ? 2.f : 3.f);
    sh += wt * ghr;
    sv += wt * gvr;
    sd += wt * 0.5f * (ghr + gvr);
    sa += wt * fabsf(ghr - gvr);
  }
#pragma unroll
  for (int off = 32; off > 0; off >>= 1) {
    sh += __shfl_xor(sh, off, 64);
    sv += __shfl_xor(sv, off, 64);
    sd += __shfl_xor(sd, off, 64);
    sa += __shfl_xor(sa, off, 64);
  }
  if ((tid & 63) == 0) {
    part[tid >> 6][0] = sh; part[tid >> 6][1] = sv;
    part[tid >> 6][2] = sd; part[tid >> 6][3] = sa;
  }
  __syncthreads();
  if (tid == 0) {
    float sc[4];
    for (int k = 0; k < 4; ++k)
      sc[k] = (part[0][k] + part[1][k] + part[2][k] + part[3][k]) * (1.f / 36864.f);
    float logits[4];
    for (int k = 0; k < 4; ++k) logits[k] = b2[k];
    for (int j = 0; j < 32; ++j) {
      float hj = b1[j];
      for (int i = 0; i < 4; ++i) hj += sc[i] * w1[j * 4 + i];
      hj = fmaxf(hj, 0.f);
      for (int k = 0; k < 4; ++k) logits[k] += hj * w2[k * 32 + j];
    }
    int idx = 0;
    float best = logits[0];
    for (int k = 1; k < 4; ++k)
      if (logits[k] > best) { best = logits[k]; idx = k; }
    flag[b] = (idx == 1) ? 1 : 0;
  }
}

// --------------------------- out-proj GEMM ---------------------------------
__global__ __launch_bounds__(256) void k_gemm(const unsigned short* __restrict__ A,
                                              const unsigned short* __restrict__ Bw,
                                              const float* __restrict__ bias,
                                              const float* __restrict__ resid,
                                              float* __restrict__ out,
                                              int K, int N) {
  __shared__ unsigned short Al[128][40];
  __shared__ unsigned short Bl[128][40];
  const int tid = threadIdx.x;
  const long m0 = (long)blockIdx.x * 128;
  const int n0 = blockIdx.y * 128;
  const int rA = tid >> 2;
  const int cp = (tid & 3) * 8;

  const unsigned short* a0p = A + (m0 + rA) * K + cp;
  const unsigned short* a1p = A + (m0 + rA + 64) * K + cp;
  const unsigned short* b0p = Bw + (long)(n0 + rA) * K + cp;
  const unsigned short* b1p = Bw + (long)(n0 + rA + 64) * K + cp;

  const int wv = tid >> 6, lane = tid & 63;
  const int wm = (wv >> 1) * 64, wn = (wv & 1) * 64;
  const int fr = lane & 15, fq = lane >> 4;

  const f32x4 zero4 = {0.f, 0.f, 0.f, 0.f};
  f32x4 acc[4][4];
#pragma unroll
  for (int i = 0; i < 4; ++i)
#pragma unroll
    for (int j = 0; j < 4; ++j) acc[i][j] = zero4;

  for (int k0 = 0; k0 < K; k0 += 32) {
    half8 va0 = *(const half8*)(a0p + k0);
    half8 va1 = *(const half8*)(a1p + k0);
    half8 vb0 = *(const half8*)(b0p + k0);
    half8 vb1 = *(const half8*)(b1p + k0);
    __syncthreads();
    *(half8*)&Al[rA][cp] = va0;
    *(half8*)&Al[rA + 64][cp] = va1;
    *(half8*)&Bl[rA][cp] = vb0;
    *(half8*)&Bl[rA + 64][cp] = vb1;
    __syncthreads();
    half8 af[4], bf[4];
#pragma unroll
    for (int i = 0; i < 4; ++i) af[i] = *(const half8*)&Al[wm + i * 16 + fr][fq * 8];
#pragma unroll
    for (int j = 0; j < 4; ++j) bf[j] = *(const half8*)&Bl[wn + j * 16 + fr][fq * 8];
#pragma unroll
    for (int i = 0; i < 4; ++i)
#pragma unroll
      for (int j = 0; j < 4; ++j)
        acc[i][j] = __builtin_amdgcn_mfma_f32_16x16x32_f16(af[i], bf[j], acc[i][j], 0, 0, 0);
  }

#pragma unroll
  for (int j = 0; j < 4; ++j) {
    const int col = n0 + wn + j * 16 + fr;
    const float bv = bias[col];
#pragma unroll
    for (int i = 0; i < 4; ++i) {
      const long mbase = m0 + wm + i * 16 + fq * 4;
#pragma unroll
      for (int r = 0; r < 4; ++r) {
        const long m = mbase + r;
        out[m * N + col] = acc[i][j][r] + bv + resid[m * N + col];
      }
    }
  }
}

// ------------------------------- GRU scan v13 -------------------------------
// 32 WGs (batch,dir) x 256 threads (4 waves). Thread t = unit t; owns the
// r,z,n rows of unit t. r-row: 32 named pinned uvec4 (128 regs, loaded ONCE).
// z,n rows: streamed from L2 per step via coalesced whhS layout (by design).
// h broadcast: 32 uniform b128 reads/wave/step. Gate math fully in-thread.
// One barrier/step. Chunk input-proj GEMM (v5's 4-wave version) on MFMA pipe.
__global__ __launch_bounds__(256, 1) void k_scan(
    const unsigned short* __restrict__ xn,
    const unsigned short* __restrict__ wcomb,
    const float* __restrict__ badj,
    const uvec4* __restrict__ whhS,
    const float* __restrict__ bhhf,
    const float* __restrict__ bhhb,
    const int* __restrict__ flag,
    unsigned short* __restrict__ ycat) {
  const int dir = blockIdx.x & 1;
  const int b = blockIdx.x >> 1;
  const uvec4* wS = whhS + (long)dir * (3 * 32 * 256);
  const float* bhh = dir ? bhhb : bhhf;
  const unsigned short* wcd = wcomb + (long)dir * (768 * 256);
  const float* bcd = badj + dir * 768;
  const int tid = threadIdx.x;
  const int wv = tid >> 6;        // 0..3
  const int lane = tid & 63;
  const int fr = lane & 15;
  const int fq = lane >> 4;
  const int fb = flag[b];

  __shared__ unsigned short xplds[CH][768];   // 48 KiB
  __shared__ unsigned short ylds[CH][256];    // 16 KiB
  __shared__ uvec4 hl4[2][32];                // h double-buffer

  const float Bnh = bhh[512 + tid];
  float hreg = 0.f;
  if (tid < 128) ((unsigned*)hl4[0])[tid] = 0;

  // ---- r-row resident: 32 named uvec4, loaded once, pinned ----
  const uvec4* rp = wS + tid;                 // gate 0, kblk-major stride 256
  uvec4 w00 = rp[0 * 256],  w01 = rp[1 * 256],  w02 = rp[2 * 256],  w03 = rp[3 * 256];
  uvec4 w04 = rp[4 * 256],  w05 = rp[5 * 256],  w06 = rp[6 * 256],  w07 = rp[7 * 256];
  uvec4 w08 = rp[8 * 256],  w09 = rp[9 * 256],  w10 = rp[10 * 256], w11 = rp[11 * 256];
  uvec4 w12 = rp[12 * 256], w13 = rp[13 * 256], w14 = rp[14 * 256], w15 = rp[15 * 256];
  uvec4 w16 = rp[16 * 256], w17 = rp[17 * 256], w18 = rp[18 * 256], w19 = rp[19 * 256];
  uvec4 w20 = rp[20 * 256], w21 = rp[21 * 256], w22 = rp[22 * 256], w23 = rp[23 * 256];
  uvec4 w24 = rp[24 * 256], w25 = rp[25 * 256], w26 = rp[26 * 256], w27 = rp[27 * 256];
  uvec4 w28 = rp[28 * 256], w29 = rp[29 * 256], w30 = rp[30 * 256], w31 = rp[31 * 256];
  asm volatile("" : "+v"(w00), "+v"(w01), "+v"(w02), "+v"(w03),
                    "+v"(w04), "+v"(w05), "+v"(w06), "+v"(w07));
  asm volatile("" : "+v"(w08), "+v"(w09), "+v"(w10), "+v"(w11),
                    "+v"(w12), "+v"(w13), "+v"(w14), "+v"(w15));
  asm volatile("" : "+v"(w16), "+v"(w17), "+v"(w18), "+v"(w19),
                    "+v"(w20), "+v"(w21), "+v"(w22), "+v"(w23));
  asm volatile("" : "+v"(w24), "+v"(w25), "+v"(w26), "+v"(w27),
                    "+v"(w28), "+v"(w29), "+v"(w30), "+v"(w31));

  const uvec4* zp = wS + 32 * 256 + tid;      // gate 1 stream base
  const uvec4* np = wS + 64 * 256 + tid;      // gate 2 stream base

  __syncthreads();

  const long xnb = (long)b * 4096;
  unsigned short* yb = ycat + (long)b * (L_ * 512) + dir * 256;

  const f32x4 zero4 = {0.f, 0.f, 0.f, 0.f};
  int pb = 0;  // current h buffer

  for (int c = 0; c < NCH; ++c) {
    const int cc = dir ? (NCH - 1 - c) : c;
    const int t0 = cc * CH;

    // ---- flush previous chunk's y from LDS to global (skip first) ----
    if (c > 0) {
      const int pt0 = (dir ? (NCH - c) : (c - 1)) * CH;
#pragma unroll
      for (int k = 0; k < 4; ++k) {
        const int idx = tid + 256 * k;
        const int tsx = idx >> 5;
        const int cl = (idx & 31) * 8;
        half8 v = *(const half8*)&ylds[tsx][cl];
        *(half8*)(yb + (long)(pt0 + tsx) * 512 + cl) = v;
      }
    }

    // ---- chunk GEMM (MFMA pipe): xplds = seq[t0..t0+31] @ wcd.T + badj ----
    {
      const unsigned short* arow0;
      const unsigned short* arow1;
      {
        int t = t0 + fr;
        int p = fb ? (((t & 63) << 6) | (t >> 6)) : t;
        arow0 = xn + (xnb + p) * 256 + fq * 8;
        t = t0 + 16 + fr;
        p = fb ? (((t & 63) << 6) | (t >> 6)) : t;
        arow1 = xn + (xnb + p) * 256 + fq * 8;
      }
#pragma unroll
      for (int hf = 0; hf < 4; ++hf) {
        f32x4 acc0[3], acc1[3];
#pragma unroll
        for (int j = 0; j < 3; ++j) { acc0[j] = zero4; acc1[j] = zero4; }
#pragma unroll
        for (int s = 0; s < 8; ++s) {
          half8 a0v = *(const half8*)(arow0 + s * 32);
          half8 a1v = *(const half8*)(arow1 + s * 32);
#pragma unroll
          for (int j = 0; j < 3; ++j) {
            const int n = wv * 192 + hf * 48 + j * 16 + fr;
            half8 bfr = *(const half8*)(wcd + (long)n * 256 + s * 32 + fq * 8);
            acc0[j] = __builtin_amdgcn_mfma_f32_16x16x32_f16(a0v, bfr, acc0[j], 0, 0, 0);
            acc1[j] = __builtin_amdgcn_mfma_f32_16x16x32_f16(a1v, bfr, acc1[j], 0, 0, 0);
          }
        }
#pragma unroll
        for (int j = 0; j < 3; ++j) {
          const int n = wv * 192 + hf * 48 + j * 16 + fr;
          const float bv = bcd[n];
#pragma unroll
          for (int r = 0; r < 4; ++r) {
            xplds[fq * 4 + r][n] = f2h(acc0[j][r] + bv);
            xplds[16 + fq * 4 + r][n] = f2h(acc1[j][r] + bv);
          }
        }
      }
    }
    __syncthreads();  // xplds ready; ylds flushed; hl4 init visible

    // ---- sequential GRU steps: r resident, z/n streamed, gates in-thread ---
    for (int lt = 0; lt < CH; ++lt) {
      const int ts = dir ? (CH - 1 - lt) : lt;
      const float xr = h2f(xplds[ts][tid]);
      const float xz = h2f(xplds[ts][256 + tid]);
      const float xnv = h2f(xplds[ts][512 + tid]);
      const uvec4* hp = hl4[pb];
      float ar0 = 0.f, ar1 = 0.f, ar2 = 0.f, ar3 = 0.f;
      float az0 = 0.f, az1 = 0.f, az2 = 0.f, az3 = 0.f;
      float an0 = 0.f, an1 = 0.f, an2 = 0.f, an3 = 0.f;
#define STEP_I(I, W)                                   \
      {                                                \
        uvec4 hv = hp[I];                              \
        uvec4 zq = zp[(I) * 256];                      \
        uvec4 nq = np[(I) * 256];                      \
        ar0 = dot2(W.x, hv.x, ar0);                    \
        ar1 = dot2(W.y, hv.y, ar1);                    \
        ar2 = dot2(W.z, hv.z, ar2);                    \
        ar3 = dot2(W.w, hv.w, ar3);                    \
        az0 = dot2(zq.x, hv.x, az0);                   \
        az1 = dot2(zq.y, hv.y, az1);                   \
        az2 = dot2(zq.z, hv.z, az2);                   \
        az3 = dot2(zq.w, hv.w, az3);                   \
        an0 = dot2(nq.x, hv.x, an0);                   \
        an1 = dot2(nq.y, hv.y, an1);                   \
        an2 = dot2(nq.z, hv.z, an2);                   \
        an3 = dot2(nq.w, hv.w, an3);                   \
      }
      STEP_I(0, w00)  STEP_I(1, w01)  STEP_I(2, w02)  STEP_I(3, w03)
      STEP_I(4, w04)  STEP_I(5, w05)  STEP_I(6, w06)  STEP_I(7, w07)
      STEP_I(8, w08)  STEP_I(9, w09)  STEP_I(10, w10) STEP_I(11, w11)
      STEP_I(12, w12) STEP_I(13, w13) STEP_I(14, w14) STEP_I(15, w15)
      STEP_I(16, w16) STEP_I(17, w17) STEP_I(18, w18) STEP_I(19, w19)
      STEP_I(20, w20) STEP_I(21, w21) STEP_I(22, w22) STEP_I(23, w23)
      STEP_I(24, w24) STEP_I(25, w25) STEP_I(26, w26) STEP_I(27, w27)
      STEP_I(28, w28) STEP_I(29, w29) STEP_I(30, w30) STEP_I(31, w31)
#undef STEP_I
      const float ghr = (ar0 + ar1) + (ar2 + ar3);
      const float ghz = (az0 + az1) + (az2 + az3);
      const float ghn = (an0 + an1) + (an2 + an3);
      const float r = sigm(xr + ghr);
      const float z = sigm(xz + ghz);
      const float n = tanhf_(xnv + r * (ghn + Bnh));
      hreg = n + z * (hreg - n);
      const unsigned short hb = f2h(hreg);
      ((unsigned short*)hl4[pb ^ 1])[tid] = hb;
      ylds[ts][tid] = hb;
      pb ^= 1;
      __syncthreads();
    }
  }
  // final chunk's y flush
  {
    const int pt0 = (dir ? 0 : (NCH - 1)) * CH;
#pragma unroll
    for (int k = 0; k < 4; ++k) {
      const int idx = tid + 256 * k;
      const int tsx = idx >> 5;
      const int cl = (idx & 31) * 8;
      half8 v = *(const half8*)&ylds[tsx][cl];
      *(half8*)(yb + (long)(pt0 + tsx) * 512 + cl) = v;
    }
  }
}

// ------------------------------- launcher ----------------------------------
extern "C" void kernel_launch(void* const* d_in, const int* in_sizes, int n_in,
                              void* d_out, int out_size, void* d_ws, size_t ws_size,
                              hipStream_t stream) {
  (void)in_sizes; (void)n_in; (void)out_size; (void)ws_size;
  const float* x     = (const float*)d_in[0];
  const float* lng   = (const float*)d_in[1];
  const float* lnb   = (const float*)d_in[2];
  const float* w1    = (const float*)d_in[3];
  const float* b1    = (const float*)d_in[4];
  const float* w2    = (const float*)d_in[5];
  const float* b2    = (const float*)d_in[6];
  const float* in_w  = (const float*)d_in[7];
  const float* in_b  = (const float*)d_in[8];
  const float* wih_f = (const float*)d_in[9];
  const float* whh_f = (const float*)d_in[10];
  const float* bih_f = (const float*)d_in[11];
  const float* bhh_f = (const float*)d_in[12];
  const float* wih_b = (const float*)d_in[13];
  const float* whh_b = (const float*)d_in[14];
  const float* bih_b = (const float*)d_in[15];
  const float* bhh_b = (const float*)d_in[16];
  const float* out_w = (const float*)d_in[17];
  const float* out_b = (const float*)d_in[18];

  char* ws = (char*)d_ws;
  unsigned short* xn     = (unsigned short*)(ws + 0);
  float*          gray   = (float*)(ws + 33554432);
  int*            flag   = (int*)(ws + 33816576);
  uvec4*          whhS   = (uvec4*)(ws + 33816832);
  unsigned short* outw16 = (unsigned short*)(ws + 34603264);
  unsigned short* wcomb  = (unsigned short*)(ws + 34865408);
  float*          badj   = (float*)(ws + 35651840);
  unsigned short* ycat   = (unsigned short*)(ws + 35658240);

  k_whhS<<<192, 256, 0, stream>>>(whh_f, whh_b, whhS);
  k_f2h<<<512, 256, 0, stream>>>(out_w, outw16, 131072);
  k_wcomb<<<1536, 256, 0, stream>>>(wih_f, wih_b, in_w, wcomb);
  k_bcomb<<<6, 256, 0, stream>>>(wih_f, wih_b, in_b, bih_f, bih_b,
                                 bhh_f, bhh_b, badj);
  k_ln<<<16384, 256, 0, stream>>>(x, lng, lnb, xn, gray);
  k_sel<<<16, 256, 0, stream>>>(gray, w1, b1, w2, b2, flag);
  k_scan<<<32, 256, 0, stream>>>(xn, wcomb, badj, whhS,
                                 bhh_f, bhh_b, flag, ycat);
  dim3 gout(512, 2);
  k_gemm<<<gout, 256, 0, stream>>>(ycat, outw16, out_b, x, (float*)d_out, 512, 256);
}